// Round 17
// baseline (378.149 us; speedup 1.0000x reference)
//
#include <hip/hip_runtime.h>

typedef __bf16 bf16x8 __attribute__((ext_vector_type(8)));
typedef float f32x4 __attribute__((ext_vector_type(4)));
typedef unsigned int uint32x4 __attribute__((ext_vector_type(4)));

#define DD 256
#define VV 1024
#define BN 16
#define KC1 36   // extended-K chunks of 8 (288/8): 32 data + c2 + zeros
#define WVA 8    // waves per block

__device__ __forceinline__ unsigned short f2bf(float f) {
    unsigned int b = __float_as_uint(f);
    b += 0x7FFFu + ((b >> 16) & 1u);
    return (unsigned short)(b >> 16);
}

// async global->LDS, 16B per lane. LDS dst must be WAVE-UNIFORM base
// (HW adds lane*16); global src is per-lane.
typedef __attribute__((address_space(3))) unsigned int lds_uint;
typedef __attribute__((address_space(1))) const unsigned int glb_uint;
__device__ __forceinline__ void dma16(const float* g, float* l) {
    __builtin_amdgcn_global_load_lds((glb_uint*)g, (lds_uint*)l, 16, 0, 0);
}

// Prep: fragment-major, sigma-permuted codebook layouts (verified R8+).
// sigma: element d -> kc = (d>>5)*4 + ((d>>2)&3), j = (d&3) + ((d>>4)&1)*4.
__global__ __launch_bounds__(256) void vq_prep_kernel(
    const float* __restrict__ cb,
    unsigned short* __restrict__ cbA,   // [V/16][KC1][16][8]
    unsigned short* __restrict__ cbB)   // [D/16][128][16][8]
{
    int v = blockIdx.x;
    int t = threadIdx.x;
    float val = cb[(size_t)v * DD + t];
    unsigned short h = f2bf(val);
    const int vtile = v >> 4, vi = v & 15;
    const int kc_t = (t >> 5) * 4 + ((t >> 2) & 3);
    const int j_t  = (t & 3) + ((t >> 4) & 1) * 4;
    cbA[(((size_t)vtile * KC1 + kc_t) * 16 + vi) * 8 + j_t] = h;
    const int kcv = (v >> 5) * 4 + ((v >> 2) & 3);
    const int jv  = (v & 3) + ((v >> 4) & 1) * 4;
    cbB[(((size_t)(t >> 4) * 128 + kcv) * 16 + (t & 15)) * 8 + jv] = h;

    float p = val * val;
#pragma unroll
    for (int d = 1; d < 64; d <<= 1) p += __shfl_xor(p, d);
    __shared__ float ps[4];
    if ((t & 63) == 0) ps[t >> 6] = p;
    __syncthreads();
    if (t < 32) {
        float c2 = ps[0] + ps[1] + ps[2] + ps[3];
        float m = -0.5f * c2;
        unsigned short hi = f2bf(m);
        float hif = __uint_as_float((unsigned int)hi << 16);
        unsigned short lo = f2bf(m - hif);
        unsigned short o = (t == 0) ? hi : ((t == 1) ? lo : (unsigned short)0);
        cbA[(((size_t)vtile * KC1 + 32 + (t >> 3)) * 16 + vi) * 8 + (t & 7)] = o;
    }
}

// Fused main: GEMM1 + no-max gumbel-softmax + prob->LDS(bf16 sigma) + GEMM2.
// Gumbel staged per-wave (4 KB regions, two 64-V halves) -> wave-local vmcnt
// waits, no block-wide gumbel barrier. LDS 48.5 KB -> 3 blocks/CU.
__global__ __launch_bounds__(512, 6) void vq_main_kernel(
    const float* __restrict__ x,          // [N][D]
    const float* __restrict__ gum,        // [N][V]
    const unsigned short* __restrict__ cbA,
    const unsigned short* __restrict__ cbB,
    float* __restrict__ out_q,            // [N][D]
    float* __restrict__ out_p)            // [N][V]
{
    __shared__ __align__(16) float xbuf[BN * DD];      // 16 KB
    __shared__ __align__(16) float gbuf[WVA * 1024];   // 32 KB; later: prob bf16
    __shared__ float sred[WVA * BN];                   // 512 B

    const int tid  = threadIdx.x;
    const int wave = tid >> 6;    // 0..7
    const int lane = tid & 63;
    const int lrow = (lane >> 4) & 3;
    const int lcol = lane & 15;
    const int row0 = blockIdx.x * BN;
    const int laneoff = lrow * 128 + lcol * 8;
    float* greg = &gbuf[wave * 1024];   // this wave's 4 KB gumbel region

    // ---- DMA issue: x rows (2/wave) then own gumbel half-0 (4 x 1KB) ----
    // gumbel region: (row r, slot16 s) at byte (r>>2)*1024 + (r&3)*256 + s*16,
    // holding gum[row0+r][hf*512 + wave*64 + (s ^ (r&7))*4 ..+3].
#pragma unroll
    for (int h = 0; h < 2; ++h) {
        const int r = wave * 2 + h;
        dma16(x + (size_t)(row0 + r) * DD + (((lane ^ (r & 7)) & 63) << 2),
              &xbuf[r * DD]);
    }
#pragma unroll
    for (int d = 0; d < 4; ++d) {
        const int r = d * 4 + (lane >> 4);
        dma16(gum + (size_t)(row0 + r) * VV + wave * 64 +
                  ((((lane & 15) ^ (r & 7))) << 2),
              &greg[d * 256]);
    }
    // x done (2 oldest of 6); own gumbel half-0 still in flight
    asm volatile("s_waitcnt vmcnt(4)" ::: "memory");
    __builtin_amdgcn_sched_barrier(0);
    __builtin_amdgcn_s_barrier();

    // ---- afr from xbuf (sigma slots) + x2 ----
    bf16x8 afr[9];
    float x2 = 0.f;
#pragma unroll
    for (int kt = 0; kt < 8; ++kt) {
        const int g1 = (kt * 8 + lrow) ^ (lcol & 7);
        const int g2 = (kt * 8 + lrow + 4) ^ (lcol & 7);
        f32x4 a = *reinterpret_cast<const f32x4*>(&xbuf[lcol * DD + g1 * 4]);
        f32x4 b = *reinterpret_cast<const f32x4*>(&xbuf[lcol * DD + g2 * 4]);
        bf16x8 fr;
#pragma unroll
        for (int j = 0; j < 4; ++j) {
            x2 += a[j] * a[j] + b[j] * b[j];
            fr[j]     = (__bf16)a[j];
            fr[j + 4] = (__bf16)b[j];
        }
        afr[kt] = fr;
    }
    x2 += __shfl_xor(x2, 16);
    x2 += __shfl_xor(x2, 32);   // full-row x2 of row lcol
    {
        uint32x4 w = {0u, 0u, 0u, 0u};
        if (lrow == 0) w[0] = 0x3F803F80u;  // bf16 1.0 pair at c2 slots
        afr[8] = __builtin_bit_cast(bf16x8, w);
    }

    // ---- GEMM1: acc[nt]: v = (nt>>2)*512 + wave*64 + (nt&3)*16 + 4lrow+r ----
    f32x4 acc[8];
#pragma unroll
    for (int nt = 0; nt < 8; ++nt) acc[nt] = (f32x4){0.f, 0.f, 0.f, 0.f};
#pragma unroll
    for (int nt = 0; nt < 8; ++nt) {
        const int vt = (nt >> 2) * 32 + wave * 4 + (nt & 3);
        const unsigned short* ap = cbA + (size_t)vt * (KC1 * 128) + laneoff;
#pragma unroll
        for (int kt = 0; kt < 9; ++kt) {
            bf16x8 cfr = __builtin_bit_cast(bf16x8,
                *reinterpret_cast<const uint32x4*>(ap + kt * 512));
            acc[nt] = __builtin_amdgcn_mfma_f32_16x16x32_bf16(cfr, afr[kt], acc[nt], 0, 0, 0);
        }
    }

    // own gumbel half-0 landed (wave-local wait, no barrier)
    asm volatile("s_waitcnt vmcnt(0)" ::: "memory");
    __builtin_amdgcn_sched_barrier(0);

    // ---- u4 half-0 reads ----
    f32x4 u4[4];
#pragma unroll
    for (int nt = 0; nt < 4; ++nt) {
        const int s = (nt * 4 + lrow) ^ (lcol & 7);
        u4[nt] = *reinterpret_cast<const f32x4*>(&greg[lcol * 64 + s * 4]);
    }
    // reads retired -> safe to overwrite region with half-1 DMA
    asm volatile("s_waitcnt lgkmcnt(0)" ::: "memory");
    __builtin_amdgcn_sched_barrier(0);
#pragma unroll
    for (int d = 0; d < 4; ++d) {
        const int r = d * 4 + (lane >> 4);
        dma16(gum + (size_t)(row0 + r) * VV + 512 + wave * 64 +
                  ((((lane & 15) ^ (r & 7))) << 2),
              &greg[d * 256]);
    }

    // ---- softmax half-0 (hides half-1 DMA) ----
    float ss = 0.f;
#pragma unroll
    for (int nt = 0; nt < 4; ++nt) {
#pragma unroll
        for (int r = 0; r < 4; ++r) {
            float u = fminf(fmaxf(u4[nt][r], 1e-10f), 1.0f - 1e-10f);
            float l2u = __builtin_amdgcn_logf(u);
            float t = u - 1.0f;
            float pp = t * (1.0f + t * (-0.5f + t * (0.33333333f + t * (-0.25f + t * 0.2f))));
            float w = (u >= 0.984375f) ? -pp : (l2u * -0.69314718f);
            float l2w = __builtin_amdgcn_logf(w);
            float d2 = fmaxf(__builtin_fmaf(-2.0f, acc[nt][r], x2), 1e-12f);
            float dist = __builtin_amdgcn_sqrtf(d2);
            float lg2 = __builtin_fmaf(-0.72134752f, dist, -0.5f * l2w);
            float e = __builtin_amdgcn_exp2f(lg2);
            acc[nt][r] = e;
            ss += e;
        }
    }

    // own gumbel half-1 landed
    asm volatile("s_waitcnt vmcnt(0)" ::: "memory");
    __builtin_amdgcn_sched_barrier(0);
#pragma unroll
    for (int nt = 0; nt < 4; ++nt) {
        const int s = (nt * 4 + lrow) ^ (lcol & 7);
        u4[nt] = *reinterpret_cast<const f32x4*>(&greg[lcol * 64 + s * 4]);
    }
    // ---- softmax half-1 ----
#pragma unroll
    for (int nt = 0; nt < 4; ++nt) {
#pragma unroll
        for (int r = 0; r < 4; ++r) {
            float u = fminf(fmaxf(u4[nt][r], 1e-10f), 1.0f - 1e-10f);
            float l2u = __builtin_amdgcn_logf(u);
            float t = u - 1.0f;
            float pp = t * (1.0f + t * (-0.5f + t * (0.33333333f + t * (-0.25f + t * 0.2f))));
            float w = (u >= 0.984375f) ? -pp : (l2u * -0.69314718f);
            float l2w = __builtin_amdgcn_logf(w);
            float d2 = fmaxf(__builtin_fmaf(-2.0f, acc[nt + 4][r], x2), 1e-12f);
            float dist = __builtin_amdgcn_sqrtf(d2);
            float lg2 = __builtin_fmaf(-0.72134752f, dist, -0.5f * l2w);
            float e = __builtin_amdgcn_exp2f(lg2);
            acc[nt + 4][r] = e;
            ss += e;
        }
    }
    ss += __shfl_xor(ss, 16);
    ss += __shfl_xor(ss, 32);   // row sum for row lcol (this wave's 128 v)

    if (lane < 16) sred[wave * 16 + lane] = ss;
    __syncthreads();   // B2: sred visible; ALL waves done with gumbel reads

    float Z = 0.f;
#pragma unroll
    for (int w = 0; w < WVA; ++w) Z += sred[w * 16 + lcol];
    const float rinv = 1.0f / Z;

    // ---- normalize; prob -> gbuf as bf16 sigma-slot tile [16][1024] ----
    // slot(v) = G*32 + lrow*8 + (nt&1)*4 + r, G = (nt>>2)*16 + wave*2 + ((nt&3)>>1)
    // pack nt (even) + nt+1 into one 16B write; XOR-swizzle elem bits 3-5 by row.
    unsigned short* pb = reinterpret_cast<unsigned short*>(gbuf);
#pragma unroll
    for (int nt = 0; nt < 8; nt += 2) {
        const int G = (nt >> 2) * 16 + wave * 2 + ((nt & 3) >> 1);
        uint32x4 pk;
#pragma unroll
        for (int h = 0; h < 2; ++h) {
#pragma unroll
            for (int r = 0; r < 4; ++r) acc[nt + h][r] *= rinv;
            __bf16 b0 = (__bf16)acc[nt + h][0], b1 = (__bf16)acc[nt + h][1];
            __bf16 b2 = (__bf16)acc[nt + h][2], b3 = (__bf16)acc[nt + h][3];
            pk[2 * h]     = (unsigned int)__builtin_bit_cast(unsigned short, b0) |
                            ((unsigned int)__builtin_bit_cast(unsigned short, b1) << 16);
            pk[2 * h + 1] = (unsigned int)__builtin_bit_cast(unsigned short, b2) |
                            ((unsigned int)__builtin_bit_cast(unsigned short, b3) << 16);
        }
        const int s = G * 32 + lrow * 8;
        *reinterpret_cast<uint32x4*>(&pb[lcol * VV + (s ^ ((lcol & 7) << 3))]) = pk;
    }
    __syncthreads();   // B3: prob tile visible

    // ---- out_p stores issued first (fly under GEMM2) ----
    {
        float* oprow = out_p + (size_t)(row0 + lcol) * VV;
#pragma unroll
        for (int nt = 0; nt < 8; ++nt) {
            const int vbase = (nt >> 2) * 512 + wave * 64 + (nt & 3) * 16 + lrow * 4;
            *reinterpret_cast<float4*>(oprow + vbase) =
                (float4){acc[nt][0], acc[nt][1], acc[nt][2], acc[nt][3]};
        }
    }

    // ---- GEMM2: out_q[16][wave*32..+31] = prob[16][1024] @ cb ----
    f32x4 q[2];
    q[0] = (f32x4){0.f, 0.f, 0.f, 0.f};
    q[1] = (f32x4){0.f, 0.f, 0.f, 0.f};
    const unsigned short* bb0 = cbB + (size_t)(wave * 2) * 16384 + laneoff;
    const unsigned short* bb1 = bb0 + 16384;

#pragma unroll 4
    for (int kt = 0; kt < 32; ++kt) {
        bf16x8 pfr = __builtin_bit_cast(bf16x8,
            *reinterpret_cast<const uint32x4*>(
                &pb[lcol * VV + ((kt * 32 + lrow * 8) ^ ((lcol & 7) << 3))]));
        bf16x8 f0 = __builtin_bit_cast(bf16x8,
            *reinterpret_cast<const uint32x4*>(bb0 + kt * 512));
        bf16x8 f1 = __builtin_bit_cast(bf16x8,
            *reinterpret_cast<const uint32x4*>(bb1 + kt * 512));
        q[0] = __builtin_amdgcn_mfma_f32_16x16x32_bf16(pfr, f0, q[0], 0, 0, 0);
        q[1] = __builtin_amdgcn_mfma_f32_16x16x32_bf16(pfr, f1, q[1], 0, 0, 0);
    }

    // ---- out_q: C[row = row0+lrow*4+r][d = wave*32 + {0,16} + lcol] ----
    {
        float* qrow0 = out_q + (size_t)(row0 + lrow * 4) * DD + wave * 32 + lcol;
#pragma unroll
        for (int r = 0; r < 4; ++r) {
            float* qr = qrow0 + r * DD;
            qr[0]  = q[0][r];
            qr[16] = q[1][r];
        }
    }
}

extern "C" void kernel_launch(void* const* d_in, const int* in_sizes, int n_in,
                              void* d_out, int out_size, void* d_ws, size_t ws_size,
                              hipStream_t stream) {
    (void)in_sizes; (void)n_in; (void)out_size; (void)ws_size;
    const float* x   = (const float*)d_in[0];   // [16,4096,256]
    const float* cb  = (const float*)d_in[1];   // [1024,256]
    const float* gum = (const float*)d_in[2];   // [65536,1024]

    const int N = 16 * 4096;
    float* out_q = (float*)d_out;                       // [N][256]
    float* out_p = out_q + (size_t)N * DD;              // [N][1024]

    unsigned short* cbA = (unsigned short*)d_ws;        // 576 KB fragment-major
    unsigned short* cbB = cbA + (size_t)64 * KC1 * 128; // 512 KB fragment-major
    vq_prep_kernel<<<VV, 256, 0, stream>>>(cb, cbA, cbB);
    vq_main_kernel<<<N / BN, 512, 0, stream>>>(x, gum, cbA, cbB, out_q, out_p);
}

// Round 18
// 327.432 us; speedup vs baseline: 1.1549x; 1.1549x over previous
//
#include <hip/hip_runtime.h>

typedef __bf16 bf16x8 __attribute__((ext_vector_type(8)));
typedef float f32x4 __attribute__((ext_vector_type(4)));
typedef unsigned int uint32x4 __attribute__((ext_vector_type(4)));

#define DD 256
#define VV 1024
#define BN 16
#define KC1 36   // extended-K chunks of 8 (288/8): 32 data + c2 + zeros
#define WVA 8    // waves per block

__device__ __forceinline__ unsigned short f2bf(float f) {
    unsigned int b = __float_as_uint(f);
    b += 0x7FFFu + ((b >> 16) & 1u);
    return (unsigned short)(b >> 16);
}

// async global->LDS, 16B per lane. LDS dst must be WAVE-UNIFORM base
// (HW adds lane*16); global src is per-lane.
typedef __attribute__((address_space(3))) unsigned int lds_uint;
typedef __attribute__((address_space(1))) const unsigned int glb_uint;
__device__ __forceinline__ void dma16(const float* g, float* l) {
    __builtin_amdgcn_global_load_lds((glb_uint*)g, (lds_uint*)l, 16, 0, 0);
}

// Prep: fragment-major, sigma-permuted codebook layouts (verified R8+).
// sigma: element d -> kc = (d>>5)*4 + ((d>>2)&3), j = (d&3) + ((d>>4)&1)*4.
__global__ __launch_bounds__(256) void vq_prep_kernel(
    const float* __restrict__ cb,
    unsigned short* __restrict__ cbA,   // [V/16][KC1][16][8]
    unsigned short* __restrict__ cbB)   // [D/16][128][16][8]
{
    int v = blockIdx.x;
    int t = threadIdx.x;
    float val = cb[(size_t)v * DD + t];
    unsigned short h = f2bf(val);
    const int vtile = v >> 4, vi = v & 15;
    const int kc_t = (t >> 5) * 4 + ((t >> 2) & 3);
    const int j_t  = (t & 3) + ((t >> 4) & 1) * 4;
    cbA[(((size_t)vtile * KC1 + kc_t) * 16 + vi) * 8 + j_t] = h;
    const int kcv = (v >> 5) * 4 + ((v >> 2) & 3);
    const int jv  = (v & 3) + ((v >> 4) & 1) * 4;
    cbB[(((size_t)(t >> 4) * 128 + kcv) * 16 + (t & 15)) * 8 + jv] = h;

    float p = val * val;
#pragma unroll
    for (int d = 1; d < 64; d <<= 1) p += __shfl_xor(p, d);
    __shared__ float ps[4];
    if ((t & 63) == 0) ps[t >> 6] = p;
    __syncthreads();
    if (t < 32) {
        float c2 = ps[0] + ps[1] + ps[2] + ps[3];
        float m = -0.5f * c2;
        unsigned short hi = f2bf(m);
        float hif = __uint_as_float((unsigned int)hi << 16);
        unsigned short lo = f2bf(m - hif);
        unsigned short o = (t == 0) ? hi : ((t == 1) ? lo : (unsigned short)0);
        cbA[(((size_t)vtile * KC1 + 32 + (t >> 3)) * 16 + vi) * 8 + (t & 7)] = o;
    }
}

// Fused main: GEMM1 + no-max gumbel-softmax + prob->LDS(bf16 sigma) + GEMM2.
// Gumbel staged per-wave (4 KB regions, two 64-V halves) -> wave-local vmcnt
// waits, no block-wide gumbel barrier. LDS 48.5 KB.
// launch_bounds (512,4): the no-spill point — (512,6) capped regs at ~85 and
// spilled 214 MB/launch (R17); reg floor of this kernel is ~95-100 unified.
__global__ __launch_bounds__(512, 4) void vq_main_kernel(
    const float* __restrict__ x,          // [N][D]
    const float* __restrict__ gum,        // [N][V]
    const unsigned short* __restrict__ cbA,
    const unsigned short* __restrict__ cbB,
    float* __restrict__ out_q,            // [N][D]
    float* __restrict__ out_p)            // [N][V]
{
    __shared__ __align__(16) float xbuf[BN * DD];      // 16 KB
    __shared__ __align__(16) float gbuf[WVA * 1024];   // 32 KB; later: prob bf16
    __shared__ float sred[WVA * BN];                   // 512 B

    const int tid  = threadIdx.x;
    const int wave = tid >> 6;    // 0..7
    const int lane = tid & 63;
    const int lrow = (lane >> 4) & 3;
    const int lcol = lane & 15;
    const int row0 = blockIdx.x * BN;
    const int laneoff = lrow * 128 + lcol * 8;
    float* greg = &gbuf[wave * 1024];   // this wave's 4 KB gumbel region

    // ---- DMA issue: x rows (2/wave) then own gumbel half-0 (4 x 1KB) ----
    // gumbel region: (row r, slot16 s) at byte (r>>2)*1024 + (r&3)*256 + s*16,
    // holding gum[row0+r][hf*512 + wave*64 + (s ^ (r&7))*4 ..+3].
#pragma unroll
    for (int h = 0; h < 2; ++h) {
        const int r = wave * 2 + h;
        dma16(x + (size_t)(row0 + r) * DD + (((lane ^ (r & 7)) & 63) << 2),
              &xbuf[r * DD]);
    }
#pragma unroll
    for (int d = 0; d < 4; ++d) {
        const int r = d * 4 + (lane >> 4);
        dma16(gum + (size_t)(row0 + r) * VV + wave * 64 +
                  ((((lane & 15) ^ (r & 7))) << 2),
              &greg[d * 256]);
    }
    // x done (2 oldest of 6); own gumbel half-0 still in flight
    asm volatile("s_waitcnt vmcnt(4)" ::: "memory");
    __builtin_amdgcn_sched_barrier(0);
    __builtin_amdgcn_s_barrier();

    // ---- afr from xbuf (sigma slots) + x2 ----
    bf16x8 afr[9];
    float x2 = 0.f;
#pragma unroll
    for (int kt = 0; kt < 8; ++kt) {
        const int g1 = (kt * 8 + lrow) ^ (lcol & 7);
        const int g2 = (kt * 8 + lrow + 4) ^ (lcol & 7);
        f32x4 a = *reinterpret_cast<const f32x4*>(&xbuf[lcol * DD + g1 * 4]);
        f32x4 b = *reinterpret_cast<const f32x4*>(&xbuf[lcol * DD + g2 * 4]);
        bf16x8 fr;
#pragma unroll
        for (int j = 0; j < 4; ++j) {
            x2 += a[j] * a[j] + b[j] * b[j];
            fr[j]     = (__bf16)a[j];
            fr[j + 4] = (__bf16)b[j];
        }
        afr[kt] = fr;
    }
    x2 += __shfl_xor(x2, 16);
    x2 += __shfl_xor(x2, 32);   // full-row x2 of row lcol
    {
        uint32x4 w = {0u, 0u, 0u, 0u};
        if (lrow == 0) w[0] = 0x3F803F80u;  // bf16 1.0 pair at c2 slots
        afr[8] = __builtin_bit_cast(bf16x8, w);
    }

    // ---- GEMM1: acc[nt]: v = (nt>>2)*512 + wave*64 + (nt&3)*16 + 4lrow+r ----
    f32x4 acc[8];
#pragma unroll
    for (int nt = 0; nt < 8; ++nt) acc[nt] = (f32x4){0.f, 0.f, 0.f, 0.f};
#pragma unroll
    for (int nt = 0; nt < 8; ++nt) {
        const int vt = (nt >> 2) * 32 + wave * 4 + (nt & 3);
        const unsigned short* ap = cbA + (size_t)vt * (KC1 * 128) + laneoff;
#pragma unroll
        for (int kt = 0; kt < 9; ++kt) {
            bf16x8 cfr = __builtin_bit_cast(bf16x8,
                *reinterpret_cast<const uint32x4*>(ap + kt * 512));
            acc[nt] = __builtin_amdgcn_mfma_f32_16x16x32_bf16(cfr, afr[kt], acc[nt], 0, 0, 0);
        }
    }

    // own gumbel half-0 landed (wave-local wait, no barrier)
    asm volatile("s_waitcnt vmcnt(0)" ::: "memory");
    __builtin_amdgcn_sched_barrier(0);

    // ---- u4 half-0 reads ----
    f32x4 u4[4];
#pragma unroll
    for (int nt = 0; nt < 4; ++nt) {
        const int s = (nt * 4 + lrow) ^ (lcol & 7);
        u4[nt] = *reinterpret_cast<const f32x4*>(&greg[lcol * 64 + s * 4]);
    }
    // reads retired -> safe to overwrite region with half-1 DMA
    asm volatile("s_waitcnt lgkmcnt(0)" ::: "memory");
    __builtin_amdgcn_sched_barrier(0);
#pragma unroll
    for (int d = 0; d < 4; ++d) {
        const int r = d * 4 + (lane >> 4);
        dma16(gum + (size_t)(row0 + r) * VV + 512 + wave * 64 +
                  ((((lane & 15) ^ (r & 7))) << 2),
              &greg[d * 256]);
    }

    // ---- softmax half-0 (hides half-1 DMA) ----
    float ss = 0.f;
#pragma unroll
    for (int nt = 0; nt < 4; ++nt) {
#pragma unroll
        for (int r = 0; r < 4; ++r) {
            float u = fminf(fmaxf(u4[nt][r], 1e-10f), 1.0f - 1e-10f);
            float l2u = __builtin_amdgcn_logf(u);
            float t = u - 1.0f;
            float pp = t * (1.0f + t * (-0.5f + t * (0.33333333f + t * (-0.25f + t * 0.2f))));
            float w = (u >= 0.984375f) ? -pp : (l2u * -0.69314718f);
            float l2w = __builtin_amdgcn_logf(w);
            float d2 = fmaxf(__builtin_fmaf(-2.0f, acc[nt][r], x2), 1e-12f);
            float dist = __builtin_amdgcn_sqrtf(d2);
            float lg2 = __builtin_fmaf(-0.72134752f, dist, -0.5f * l2w);
            float e = __builtin_amdgcn_exp2f(lg2);
            acc[nt][r] = e;
            ss += e;
        }
    }

    // own gumbel half-1 landed
    asm volatile("s_waitcnt vmcnt(0)" ::: "memory");
    __builtin_amdgcn_sched_barrier(0);
#pragma unroll
    for (int nt = 0; nt < 4; ++nt) {
        const int s = (nt * 4 + lrow) ^ (lcol & 7);
        u4[nt] = *reinterpret_cast<const f32x4*>(&greg[lcol * 64 + s * 4]);
    }
    // ---- softmax half-1 ----
#pragma unroll
    for (int nt = 0; nt < 4; ++nt) {
#pragma unroll
        for (int r = 0; r < 4; ++r) {
            float u = fminf(fmaxf(u4[nt][r], 1e-10f), 1.0f - 1e-10f);
            float l2u = __builtin_amdgcn_logf(u);
            float t = u - 1.0f;
            float pp = t * (1.0f + t * (-0.5f + t * (0.33333333f + t * (-0.25f + t * 0.2f))));
            float w = (u >= 0.984375f) ? -pp : (l2u * -0.69314718f);
            float l2w = __builtin_amdgcn_logf(w);
            float d2 = fmaxf(__builtin_fmaf(-2.0f, acc[nt + 4][r], x2), 1e-12f);
            float dist = __builtin_amdgcn_sqrtf(d2);
            float lg2 = __builtin_fmaf(-0.72134752f, dist, -0.5f * l2w);
            float e = __builtin_amdgcn_exp2f(lg2);
            acc[nt + 4][r] = e;
            ss += e;
        }
    }
    ss += __shfl_xor(ss, 16);
    ss += __shfl_xor(ss, 32);   // row sum for row lcol (this wave's 128 v)

    if (lane < 16) sred[wave * 16 + lane] = ss;
    __syncthreads();   // B2: sred visible; ALL waves done with gumbel reads

    float Z = 0.f;
#pragma unroll
    for (int w = 0; w < WVA; ++w) Z += sred[w * 16 + lcol];
    const float rinv = 1.0f / Z;

    // ---- normalize; prob -> gbuf as bf16 sigma-slot tile [16][1024] ----
    // slot(v) = G*32 + lrow*8 + (nt&1)*4 + r, G = (nt>>2)*16 + wave*2 + ((nt&3)>>1)
    // pack nt (even) + nt+1 into one 16B write; XOR-swizzle elem bits 3-5 by row.
    unsigned short* pb = reinterpret_cast<unsigned short*>(gbuf);
#pragma unroll
    for (int nt = 0; nt < 8; nt += 2) {
        const int G = (nt >> 2) * 16 + wave * 2 + ((nt & 3) >> 1);
        uint32x4 pk;
#pragma unroll
        for (int h = 0; h < 2; ++h) {
#pragma unroll
            for (int r = 0; r < 4; ++r) acc[nt + h][r] *= rinv;
            __bf16 b0 = (__bf16)acc[nt + h][0], b1 = (__bf16)acc[nt + h][1];
            __bf16 b2 = (__bf16)acc[nt + h][2], b3 = (__bf16)acc[nt + h][3];
            pk[2 * h]     = (unsigned int)__builtin_bit_cast(unsigned short, b0) |
                            ((unsigned int)__builtin_bit_cast(unsigned short, b1) << 16);
            pk[2 * h + 1] = (unsigned int)__builtin_bit_cast(unsigned short, b2) |
                            ((unsigned int)__builtin_bit_cast(unsigned short, b3) << 16);
        }
        const int s = G * 32 + lrow * 8;
        *reinterpret_cast<uint32x4*>(&pb[lcol * VV + (s ^ ((lcol & 7) << 3))]) = pk;
    }
    __syncthreads();   // B3: prob tile visible

    // ---- out_p stores issued first (fly under GEMM2) ----
    {
        float* oprow = out_p + (size_t)(row0 + lcol) * VV;
#pragma unroll
        for (int nt = 0; nt < 8; ++nt) {
            const int vbase = (nt >> 2) * 512 + wave * 64 + (nt & 3) * 16 + lrow * 4;
            *reinterpret_cast<float4*>(oprow + vbase) =
                (float4){acc[nt][0], acc[nt][1], acc[nt][2], acc[nt][3]};
        }
    }

    // ---- GEMM2: out_q[16][wave*32..+31] = prob[16][1024] @ cb ----
    f32x4 q[2];
    q[0] = (f32x4){0.f, 0.f, 0.f, 0.f};
    q[1] = (f32x4){0.f, 0.f, 0.f, 0.f};
    const unsigned short* bb0 = cbB + (size_t)(wave * 2) * 16384 + laneoff;
    const unsigned short* bb1 = bb0 + 16384;

#pragma unroll 4
    for (int kt = 0; kt < 32; ++kt) {
        bf16x8 pfr = __builtin_bit_cast(bf16x8,
            *reinterpret_cast<const uint32x4*>(
                &pb[lcol * VV + ((kt * 32 + lrow * 8) ^ ((lcol & 7) << 3))]));
        bf16x8 f0 = __builtin_bit_cast(bf16x8,
            *reinterpret_cast<const uint32x4*>(bb0 + kt * 512));
        bf16x8 f1 = __builtin_bit_cast(bf16x8,
            *reinterpret_cast<const uint32x4*>(bb1 + kt * 512));
        q[0] = __builtin_amdgcn_mfma_f32_16x16x32_bf16(pfr, f0, q[0], 0, 0, 0);
        q[1] = __builtin_amdgcn_mfma_f32_16x16x32_bf16(pfr, f1, q[1], 0, 0, 0);
    }

    // ---- out_q: C[row = row0+lrow*4+r][d = wave*32 + {0,16} + lcol] ----
    {
        float* qrow0 = out_q + (size_t)(row0 + lrow * 4) * DD + wave * 32 + lcol;
#pragma unroll
        for (int r = 0; r < 4; ++r) {
            float* qr = qrow0 + r * DD;
            qr[0]  = q[0][r];
            qr[16] = q[1][r];
        }
    }
}

extern "C" void kernel_launch(void* const* d_in, const int* in_sizes, int n_in,
                              void* d_out, int out_size, void* d_ws, size_t ws_size,
                              hipStream_t stream) {
    (void)in_sizes; (void)n_in; (void)out_size; (void)ws_size;
    const float* x   = (const float*)d_in[0];   // [16,4096,256]
    const float* cb  = (const float*)d_in[1];   // [1024,256]
    const float* gum = (const float*)d_in[2];   // [65536,1024]

    const int N = 16 * 4096;
    float* out_q = (float*)d_out;                       // [N][256]
    float* out_p = out_q + (size_t)N * DD;              // [N][1024]

    unsigned short* cbA = (unsigned short*)d_ws;        // 576 KB fragment-major
    unsigned short* cbB = cbA + (size_t)64 * KC1 * 128; // 512 KB fragment-major
    vq_prep_kernel<<<VV, 256, 0, stream>>>(cb, cbA, cbB);
    vq_main_kernel<<<N / BN, 512, 0, stream>>>(x, gum, cbA, cbB, out_q, out_p);
}